// Round 11
// baseline (480.263 us; speedup 1.0000x reference)
//
#include <hip/hip_runtime.h>
#include <hip/hip_bf16.h>
#include <stdint.h>

// =====================================================================
// SparseAutoencoder forward:
//   pre     = x @ enc_w.T + enc_b          [B, L]
//   latents = topk_sparsify(pre, k)        [B, L] (k-sparse by |value|)
//   recon   = latents @ dec_w.T + dec_b    [B, D]
// d_out = concat(recon, latents, pre) flat, f32.
// B=4096, D=768, L=16384, k=32.
//
// Fast path:
//   - 1-pass bf16 MFMA encoder, 256x256 tile (512 thr / 8 waves of
//     128x64), 2-phase dbuf, W-reuse-major XCD mapping. NT stores for
//     pre AND latents-zero (zero-fill fused into epilogue, overlapping
//     the 268MB zero stream with staging/MFMA). NT keeps L3 clean so
//     the A/W panels stay resident (round-10: +95us from this alone).
//   - select_refine: pure NT read-scan (no zero-fill), sampled-threshold
//     collect, u64-key rank, margin-gated exact f32 recompute of
//     boundary zone (m = 1.2e-3*||x|| ~ 34 sigma).
//   - sparse decoder from compact list with bf16 weights, nt recon store.
// Fallback: round-1 f32 vector path (shape mismatch only).
// =====================================================================

typedef __attribute__((ext_vector_type(8))) short bf16x8;
typedef __attribute__((ext_vector_type(4))) float f32x4;

__device__ __forceinline__ ushort f2bf_rne(float v) {
    unsigned u = __float_as_uint(v);
    return (ushort)((u + 0x7fffu + ((u >> 16) & 1u)) >> 16);
}
__device__ __forceinline__ float bf2f(ushort h) {
    return __uint_as_float(((unsigned)h) << 16);
}

// ---------------------------------------------------------------
// pack: X[rows][K] f32 -> Ph bf16 in MFMA fragment order:
//   P[r16][kt][lane][8], lane holds row r16*16+(lane&15),
//   k = kt*32 + (lane>>4)*8 + i   (mfma_f32_16x16x32_bf16 A/B^T layout)
// ---------------------------------------------------------------
__global__ __launch_bounds__(256)
void pack_bf16(const float* __restrict__ X, ushort* __restrict__ Ph,
               int R16KT, int KT, int K)
{
    int t = blockIdx.x * 256 + threadIdx.x;
    if (t >= R16KT * 64) return;
    int lane = t & 63;
    int rest = t >> 6;
    int r16 = rest / KT, kt = rest - r16 * KT;
    int row = (r16 << 4) + (lane & 15);
    int k0  = (kt << 5) + ((lane >> 4) << 3);
    const float* src = X + (size_t)row * K + k0;

    uint hw[4];
    #pragma unroll
    for (int i = 0; i < 4; ++i) {
        float v0 = src[2 * i], v1 = src[2 * i + 1];
        hw[i] = (uint)f2bf_rne(v0) | ((uint)f2bf_rne(v1) << 16);
    }
    *reinterpret_cast<uint4*>(Ph + (size_t)t * 8) = make_uint4(hw[0], hw[1], hw[2], hw[3]);
}

// ---------------------------------------------------------------
// encoder MFMA GEMM (1-pass, BK=32, 2-phase dbuf, 256x256 tile):
//   C = Ah*Wh^T + bias;  Lat = 0  (both NT stores)
// 512 threads / 8 waves (2x4), each wave 128x64 = 8x4 frags 16x16x32.
// Per K-iter: stage 32KB (A 16KB + W 16KB), 12 ds_read + 32 MFMA/wave.
// ---------------------------------------------------------------
__global__ __launch_bounds__(512, 2)
void encoder_mfma256(const ushort* __restrict__ Ah, const ushort* __restrict__ Wh,
                     const float* __restrict__ bias, float* __restrict__ C,
                     float* __restrict__ Lat, int M, int N, int K)
{
    __shared__ ushort lds[2][16384];   // 2 x 32KB: A [0,8192) | W [8192,16384)
    const int KT = K >> 5;
    const int tid  = threadIdx.x;
    const int lane = tid & 63;
    const int wid  = tid >> 6;          // 0..7

    // W-reuse-major XCD mapping (requires (M/256) % 8 == 0, launch-checked)
    const int gy    = M >> 8;           // 256-row panels
    const int rpx   = gy >> 3;          // panels per XCD
    const int xcd   = blockIdx.x & 7;
    const int local = blockIdx.x >> 3;
    const int by    = xcd * rpx + (local % rpx);
    const int bx    = local / rpx;

    const int wr = wid >> 2;            // 0..1 (row half)
    const int wc = wid & 3;             // 0..3 (col quarter)

    f32x4 acc[8][4];
    #pragma unroll
    for (int m = 0; m < 8; ++m)
        #pragma unroll
        for (int n = 0; n < 4; ++n) acc[m][n] = (f32x4){0.f, 0.f, 0.f, 0.f};

    // stage 32 chunks of 1KB into lds[buf]; wave w stages chunks [w*4,w*4+4)
    auto STAGE = [&](int buf, int kt) {
        #pragma unroll
        for (int c0 = 0; c0 < 4; ++c0) {
            int c   = (wid << 2) + c0;                  // 0..31
            int fr  = c & 15;                            // r16 group in tile
            int rb  = ((c < 16) ? (by << 4) : (bx << 4)) + fr;
            const ushort* g = ((c < 16) ? Ah : Wh) + (((size_t)rb * KT + kt) * 64 + lane) * 8;
            ushort* dst = &lds[buf][c * 512];
            __builtin_amdgcn_global_load_lds(
                (const __attribute__((address_space(1))) unsigned int*)g,
                (__attribute__((address_space(3))) unsigned int*)dst, 16, 0, 0);
        }
    };

    STAGE(0, 0);
    __syncthreads();                // prologue: buf0 ready

    int cur = 0;
    for (int kt = 0; kt < KT; ++kt) {
        if (kt + 1 < KT) STAGE(cur ^ 1, kt + 1);   // issue next-tile loads FIRST

        bf16x8 ah[8], bh[4];
        #pragma unroll
        for (int m = 0; m < 8; ++m)
            ah[m] = *reinterpret_cast<const bf16x8*>(&lds[cur][((wr << 3) + m) * 512 + lane * 8]);
        #pragma unroll
        for (int n = 0; n < 4; ++n)
            bh[n] = *reinterpret_cast<const bf16x8*>(&lds[cur][8192 + ((wc << 2) + n) * 512 + lane * 8]);

        #pragma unroll
        for (int m = 0; m < 8; ++m)
            #pragma unroll
            for (int n = 0; n < 4; ++n)
                acc[m][n] = __builtin_amdgcn_mfma_f32_16x16x32_bf16(ah[m], bh[n], acc[m][n], 0, 0, 0);

        __syncthreads();            // drains next-tile loads (overlapped w/ MFMA)
        cur ^= 1;
    }

    // epilogue: C/D layout col=lane&15, row=(lane>>4)*4+reg
    // NT stores for pre AND the fused latents zero-fill.
    const int r_in = (lane >> 4) << 2;
    const int c_in = lane & 15;
    #pragma unroll
    for (int n = 0; n < 4; ++n) {
        const int gc = (bx << 8) + (wc << 6) + (n << 4) + c_in;
        const float bv = bias[gc];
        #pragma unroll
        for (int m = 0; m < 8; ++m) {
            const int gr0 = (by << 8) + (wr << 7) + (m << 4) + r_in;
            #pragma unroll
            for (int q = 0; q < 4; ++q) {
                __builtin_nontemporal_store(acc[m][n][q] + bv,
                                            &C[(size_t)(gr0 + q) * N + gc]);
                __builtin_nontemporal_store(0.0f,
                                            &Lat[(size_t)(gr0 + q) * N + gc]);
            }
        }
    }
}

// ---------------------------------------------------------------
// select_refine: per row (latents already zeroed by encoder),
//  1) stage x; 2) sampled threshold (256 samples; tiers), collect |v|>=t
//     (NT loads: pre has no reuse; keep enc_w/x in L3 for zone gathers)
//  3) u64-key rank -> approx k-th (tk)
//  4) zone = |a - tk| <= m -> exact f32 recompute (cooperative dots)
//  5) final = {a > tk+m} + top(k - A) of zone by exact value
//  6) deterministic slot ranking; scatter latents, emit (idx,val) list
// ---------------------------------------------------------------
#define SR_CAP 1024
#define SR_ZCAP 128

__global__ __launch_bounds__(256, 8)
void select_refine(const float* __restrict__ pre, const float* __restrict__ x,
                   const float* __restrict__ enc_w, const float* __restrict__ enc_b,
                   float* __restrict__ latents, int* __restrict__ sel_idx,
                   float* __restrict__ sel_val, const int* __restrict__ kptr,
                   int D, int L)
{
    const int b   = blockIdx.x;
    const int tid = threadIdx.x;
    const float* row = pre + (size_t)b * L;
    float* lrow = latents + (size_t)b * L;

    __shared__ float    xs[768];
    __shared__ float    smp[256];
    __shared__ float    sthr[3];     // [0]=rank1 (~L/128), [1]=rank3 (~L/64), [2]=rank7 (~L/32)
    __shared__ int      cnt;
    __shared__ unsigned long long lkey[SR_CAP];
    __shared__ float    lval[SR_CAP];
    __shared__ float    s_tk;
    __shared__ float    s_xn2;
    __shared__ int      zidx[SR_ZCAP];
    __shared__ float    zval[SR_ZCAP];
    __shared__ int      zn;
    __shared__ int      fin_n;
    __shared__ int      fin_i[64];
    __shared__ float    fin_v[64];
    __shared__ float    red[4];

    int k = *kptr; if (k > 64) k = 64; if (k < 1) k = 1;

    // ---- stage x row; compute ||x||^2 for margin scaling ----
    float xn2p = 0.f;
    for (int i = tid; i < D; i += 256) {
        float v = x[(size_t)b * D + i];
        xs[i] = v;
        xn2p = fmaf(v, v, xn2p);
    }
    #pragma unroll
    for (int off = 32; off > 0; off >>= 1) xn2p += __shfl_down(xn2p, off);
    if ((tid & 63) == 0) red[tid >> 6] = xn2p;
    if (tid == 0) { zn = 0; fin_n = 0; }
    __syncthreads();
    if (tid == 0) s_xn2 = red[0] + red[1] + red[2] + red[3];

    // ---- samples + threshold tiers ----
    const int stride = L >> 8;
    smp[tid] = fabsf(row[(size_t)tid * stride]);
    __syncthreads();
    {
        float s = smp[tid];
        int r = 0;
        for (int j = 0; j < 256; ++j) {
            float o = smp[j];
            r += (o > s || (o == s && j < tid)) ? 1 : 0;
        }
        if (r == 1) sthr[0] = s;   // overflow retry
        if (r == 3) sthr[1] = s;   // primary (~256 survivors)
        if (r == 7) sthr[2] = s;   // underflow retry (~512)
    }
    __syncthreads();

    // ---- collect with retry tiers (NT loads of pre) ----
    float t = sthr[1];
    int n = 0;
    for (int attempt = 0; attempt < 2; ++attempt) {
        __syncthreads();
        if (tid == 0) cnt = 0;
        __syncthreads();
        for (int i = tid * 4; i < L; i += 1024) {
            f32x4 v = __builtin_nontemporal_load(
                reinterpret_cast<const f32x4*>(row + i));
            float vv[4] = {v.x, v.y, v.z, v.w};
            #pragma unroll
            for (int j = 0; j < 4; ++j) {
                float av = fabsf(vv[j]);
                if (av >= t) {
                    int p = atomicAdd(&cnt, 1);
                    if (p < SR_CAP) {
                        lkey[p] = ((unsigned long long)__float_as_uint(av) << 32)
                                  | (unsigned)(~(i + j));
                        lval[p] = vv[j];
                    }
                }
            }
        }
        __syncthreads();
        n = cnt;
        if (n >= 48 && n <= SR_CAP) break;
        t = (n < 48) ? sthr[2] : sthr[0];
    }
    if (n > SR_CAP) n = SR_CAP;
    if (k > n) k = n;

    // ---- rank pass: find approx k-th largest (tk) ----
    for (int i = tid; i < n; i += 256) {
        unsigned long long ki = lkey[i];
        int rk = 0;
        for (int j = 0; j < n; ++j) rk += (lkey[j] > ki) ? 1 : 0;
        if (rk == k - 1) s_tk = fabsf(lval[i]);
    }
    __syncthreads();

    const float tk = s_tk;
    // margin: err sigma ~3.5e-5*||x||; need >= 2*e_max (~12 sigma). 34 sigma.
    const float m  = 1.2e-3f * sqrtf(s_xn2);

    // ---- partition: clear-selected (a > tk+m) vs zone (|a-tk| <= m) ----
    for (int i = tid; i < n; i += 256) {
        float a = fabsf(lval[i]);
        if (a > tk + m) {
            int p = atomicAdd(&fin_n, 1);     // guaranteed < k
            fin_i[p] = (int)(~(unsigned)lkey[i]);
            fin_v[p] = lval[i];
        } else if (a >= tk - m) {
            int zp = atomicAdd(&zn, 1);
            if (zp < SR_ZCAP) zidx[zp] = (int)(~(unsigned)lkey[i]);
        }
    }
    __syncthreads();
    const int A  = fin_n;
    const int nz = (zn < SR_ZCAP) ? zn : SR_ZCAP;

    // ---- exact f32 dots for zone members ----
    for (int z = 0; z < nz; ++z) {
        const int l = zidx[z];
        const float* wrow = enc_w + (size_t)l * D;
        float s = 0.f;
        for (int d = tid; d < D; d += 256) s = fmaf(xs[d], wrow[d], s);
        #pragma unroll
        for (int off = 32; off > 0; off >>= 1) s += __shfl_down(s, off);
        if ((tid & 63) == 0) red[tid >> 6] = s;
        __syncthreads();
        if (tid == 0) zval[z] = red[0] + red[1] + red[2] + red[3] + enc_b[l];
        __syncthreads();
    }

    // ---- select top (k - A) of zone by exact (|value| desc, idx asc) ----
    const int k2 = k - A;
    if (tid < nz) {
        float az = fabsf(zval[tid]);
        int   iz = zidx[tid];
        int rz = 0;
        for (int j = 0; j < nz; ++j) {
            float aj = fabsf(zval[j]);
            rz += (aj > az || (aj == az && zidx[j] < iz)) ? 1 : 0;
        }
        if (rz < k2) {
            int p = atomicAdd(&fin_n, 1);
            if (p < 64) { fin_i[p] = iz; fin_v[p] = zval[tid]; }
        }
    }
    __syncthreads();

    // ---- deterministic final slots + writes (latents pre-zeroed) ----
    int fn = fin_n; if (fn > 64) fn = 64;
    if (tid < fn) {
        float av = fabsf(fin_v[tid]);
        int   ii = fin_i[tid];
        int fr = 0;
        for (int j = 0; j < fn; ++j) {
            float aj = fabsf(fin_v[j]);
            fr += (aj > av || (aj == av && fin_i[j] < ii)) ? 1 : 0;
        }
        sel_idx[(size_t)b * 64 + fr] = ii;
        sel_val[(size_t)b * 64 + fr] = fin_v[tid];
        lrow[ii] = fin_v[tid];
    }
    if (tid >= fn && tid < k) {          // pathological safety fill
        sel_idx[(size_t)b * 64 + tid] = 0;
        sel_val[(size_t)b * 64 + tid] = 0.f;
    }
}

// ---------------------------------------------------------------
// dec_w transpose: W[D][L] f32 -> WT[L][D] bf16
// ---------------------------------------------------------------
__global__ void transpose_bf16(const float* __restrict__ W, ushort* __restrict__ WT,
                               int D, int L)
{
    __shared__ float tile[32][33];
    const int l0 = blockIdx.x * 32;
    const int d0 = blockIdx.y * 32;
    const int tx = threadIdx.x;
    const int ty = threadIdx.y;
    for (int i = ty; i < 32; i += 8)
        tile[i][tx] = W[(size_t)(d0 + i) * L + (l0 + tx)];
    __syncthreads();
    for (int i = ty; i < 32; i += 8)
        WT[(size_t)(l0 + i) * D + (d0 + tx)] = f2bf_rne(tile[tx][i]);
}

// ---------------------------------------------------------------
// sparse decoder from compact list (bf16 weights), NT recon stores
// ---------------------------------------------------------------
__global__ __launch_bounds__(256)
void decoder_selb(const int* __restrict__ sel_idx, const float* __restrict__ sel_val,
                  const ushort* __restrict__ WT, const float* __restrict__ dbias,
                  float* __restrict__ recon, const int* __restrict__ kptr, int D)
{
    const int b = blockIdx.x;
    const int tid = threadIdx.x;
    int k = *kptr; if (k > 64) k = 64; if (k < 1) k = 1;
    __shared__ int   si[64];
    __shared__ float sv[64];
    if (tid < k) { si[tid] = sel_idx[(size_t)b * 64 + tid]; sv[tid] = sel_val[(size_t)b * 64 + tid]; }
    __syncthreads();
    float a0 = 0.f, a1 = 0.f, a2 = 0.f;
    for (int j = 0; j < k; ++j) {
        const ushort* w = WT + (size_t)si[j] * D;
        const float v = sv[j];
        if (tid < D)        a0 = fmaf(v, bf2f(w[tid]),       a0);
        if (tid + 256 < D)  a1 = fmaf(v, bf2f(w[tid + 256]), a1);
        if (tid + 512 < D)  a2 = fmaf(v, bf2f(w[tid + 512]), a2);
    }
    if (tid < D)
        __builtin_nontemporal_store(a0 + dbias[tid],       &recon[(size_t)b * D + tid]);
    if (tid + 256 < D)
        __builtin_nontemporal_store(a1 + dbias[tid + 256], &recon[(size_t)b * D + tid + 256]);
    if (tid + 512 < D)
        __builtin_nontemporal_store(a2 + dbias[tid + 512], &recon[(size_t)b * D + tid + 512]);
}

// =====================================================================
// ============== round-1 fallback kernels (f32 path) ==================
// =====================================================================
#define BM 128
#define BN 128
#define BKT 16

__global__ __launch_bounds__(256, 2)
void encoder_gemm(const float* __restrict__ A, const float* __restrict__ Bw,
                  const float* __restrict__ bias, float* __restrict__ C,
                  int M, int N, int K)
{
    __shared__ float As[BKT][BM + 4];
    __shared__ float Bs[BKT][BN + 4];
    const int tid  = threadIdx.x;
    const int row0 = blockIdx.y * BM;
    const int col0 = blockIdx.x * BN;
    const int lrow = tid >> 2;
    const int lc4  = (tid & 3) * 4;
    const int ty = tid >> 4;
    const int tx = tid & 15;
    float acc[2][2][4][4];
    #pragma unroll
    for (int a = 0; a < 2; ++a)
        #pragma unroll
        for (int b = 0; b < 2; ++b)
            #pragma unroll
            for (int i = 0; i < 4; ++i)
                #pragma unroll
                for (int j = 0; j < 4; ++j) acc[a][b][i][j] = 0.f;
    for (int k0 = 0; k0 < K; k0 += BKT) {
        float4 a0 = *reinterpret_cast<const float4*>(A + (size_t)(row0 + lrow)      * K + k0 + lc4);
        float4 a1 = *reinterpret_cast<const float4*>(A + (size_t)(row0 + lrow + 64) * K + k0 + lc4);
        float4 b0 = *reinterpret_cast<const float4*>(Bw + (size_t)(col0 + lrow)      * K + k0 + lc4);
        float4 b1 = *reinterpret_cast<const float4*>(Bw + (size_t)(col0 + lrow + 64) * K + k0 + lc4);
        __syncthreads();
        As[lc4 + 0][lrow] = a0.x; As[lc4 + 1][lrow] = a0.y;
        As[lc4 + 2][lrow] = a0.z; As[lc4 + 3][lrow] = a0.w;
        As[lc4 + 0][lrow + 64] = a1.x; As[lc4 + 1][lrow + 64] = a1.y;
        As[lc4 + 2][lrow + 64] = a1.z; As[lc4 + 3][lrow + 64] = a1.w;
        Bs[lc4 + 0][lrow] = b0.x; Bs[lc4 + 1][lrow] = b0.y;
        Bs[lc4 + 2][lrow] = b0.z; Bs[lc4 + 3][lrow] = b0.w;
        Bs[lc4 + 0][lrow + 64] = b1.x; Bs[lc4 + 1][lrow + 64] = b1.y;
        Bs[lc4 + 2][lrow + 64] = b1.z; Bs[lc4 + 3][lrow + 64] = b1.w;
        __syncthreads();
        #pragma unroll
        for (int kk = 0; kk < BKT; ++kk) {
            float av[2][4], bv[2][4];
            *reinterpret_cast<float4*>(av[0]) = *reinterpret_cast<const float4*>(&As[kk][ty * 4]);
            *reinterpret_cast<float4*>(av[1]) = *reinterpret_cast<const float4*>(&As[kk][ty * 4 + 64]);
            *reinterpret_cast<float4*>(bv[0]) = *reinterpret_cast<const float4*>(&Bs[kk][tx * 4]);
            *reinterpret_cast<float4*>(bv[1]) = *reinterpret_cast<const float4*>(&Bs[kk][tx * 4 + 64]);
            #pragma unroll
            for (int a = 0; a < 2; ++a)
                #pragma unroll
                for (int i = 0; i < 4; ++i)
                    #pragma unroll
                    for (int b = 0; b < 2; ++b)
                        #pragma unroll
                        for (int j = 0; j < 4; ++j)
                            acc[a][b][i][j] = fmaf(av[a][i], bv[b][j], acc[a][b][i][j]);
        }
    }
    #pragma unroll
    for (int a = 0; a < 2; ++a)
        #pragma unroll
        for (int i = 0; i < 4; ++i) {
            const int r = row0 + a * 64 + ty * 4 + i;
            #pragma unroll
            for (int b = 0; b < 2; ++b) {
                const int c = col0 + b * 64 + tx * 4;
                float4 o;
                o.x = acc[a][b][i][0] + bias[c + 0];
                o.y = acc[a][b][i][1] + bias[c + 1];
                o.z = acc[a][b][i][2] + bias[c + 2];
                o.w = acc[a][b][i][3] + bias[c + 3];
                *reinterpret_cast<float4*>(C + (size_t)r * N + c) = o;
            }
        }
}

__global__ __launch_bounds__(256)
void topk_kernel(const float* __restrict__ pre, float* __restrict__ latents,
                 const int* __restrict__ kptr, int L)
{
    const int b   = blockIdx.x;
    const int tid = threadIdx.x;
    int k = *kptr; if (k > 64) k = 64; if (k < 1) k = 1;
    const float* row = pre + (size_t)b * L;
    __shared__ unsigned hist[2048];
    __shared__ unsigned coarse[256];
    __shared__ unsigned sh_cgt, sh_prefix;
    __shared__ int      tie_n;
    __shared__ int      tie_idx[1024];
    __shared__ float    tie_val[1024];
    unsigned cgt = 0, prefix = 0;
    for (int level = 0; level < 3; ++level) {
        const int nb     = (level == 0) ? 2048 : 1024;
        const int shift  = (level == 0) ? 20 : (level == 1 ? 10 : 0);
        const int pshift = (level == 1) ? 20 : 10;
        for (int i = tid; i < nb; i += 256) hist[i] = 0;
        __syncthreads();
        for (int i = tid * 4; i < L; i += 1024) {
            float4 v = *reinterpret_cast<const float4*>(row + i);
            float vv[4] = {v.x, v.y, v.z, v.w};
            #pragma unroll
            for (int j = 0; j < 4; ++j) {
                unsigned key = __float_as_uint(vv[j]) & 0x7fffffffu;
                if (level == 0 || (key >> pshift) == prefix)
                    atomicAdd(&hist[(key >> shift) & (nb - 1)], 1u);
            }
        }
        __syncthreads();
        const int per = nb / 256;
        unsigned s = 0;
        for (int j = 0; j < per; ++j) s += hist[tid * per + j];
        coarse[tid] = s;
        __syncthreads();
        if (tid == 0) {
            unsigned run = cgt;
            int bin = 0;
            for (int c = 255; c >= 0; --c) {
                if (run + coarse[c] >= (unsigned)k) {
                    bin = c * per + per - 1;
                    for (; bin > c * per; --bin) {
                        if (run + hist[bin] >= (unsigned)k) break;
                        run += hist[bin];
                    }
                    break;
                }
                run += coarse[c];
            }
            sh_cgt = run;
            sh_prefix = (level == 0) ? (unsigned)bin : ((prefix << 10) | (unsigned)bin);
        }
        __syncthreads();
        cgt = sh_cgt; prefix = sh_prefix;
        __syncthreads();
    }
    const unsigned T = prefix;
    const int r = k - (int)cgt;
    if (tid == 0) tie_n = 0;
    __syncthreads();
    float* lrow = latents + (size_t)b * L;
    for (int i = tid * 4; i < L; i += 1024) {
        float4 v = *reinterpret_cast<const float4*>(row + i);
        float vv[4] = {v.x, v.y, v.z, v.w};
        #pragma unroll
        for (int j = 0; j < 4; ++j) {
            unsigned key = __float_as_uint(vv[j]) & 0x7fffffffu;
            if (key > T) {
                lrow[i + j] = vv[j];
            } else if (key == T) {
                int p = atomicAdd(&tie_n, 1);
                if (p < 1024) { tie_idx[p] = i + j; tie_val[p] = vv[j]; }
            }
        }
    }
    __syncthreads();
    if (tid == 0) {
        int nn = tie_n; if (nn > 1024) nn = 1024;
        for (int a = 1; a < nn; ++a) {
            int ia = tie_idx[a]; float va = tie_val[a];
            int c = a - 1;
            while (c >= 0 && tie_idx[c] > ia) {
                tie_idx[c + 1] = tie_idx[c]; tie_val[c + 1] = tie_val[c]; --c;
            }
            tie_idx[c + 1] = ia; tie_val[c + 1] = va;
        }
        int take = r < nn ? r : nn;
        for (int a = 0; a < take; ++a) lrow[tie_idx[a]] = tie_val[a];
    }
}

__global__ void transpose_kernel(const float* __restrict__ W, float* __restrict__ WT,
                                 int D, int L)
{
    __shared__ float tile[32][33];
    const int l0 = blockIdx.x * 32;
    const int d0 = blockIdx.y * 32;
    const int tx = threadIdx.x;
    const int ty = threadIdx.y;
    for (int i = ty; i < 32; i += 8)
        tile[i][tx] = W[(size_t)(d0 + i) * L + (l0 + tx)];
    __syncthreads();
    for (int i = ty; i < 32; i += 8)
        WT[(size_t)(l0 + i) * D + (d0 + tx)] = tile[tx][i];
}

__global__ __launch_bounds__(256)
void decoder_kernel(const float* __restrict__ latents, const float* __restrict__ WT,
                    const float* __restrict__ Wfall, const float* __restrict__ dbias,
                    float* __restrict__ recon, int L, int D, int useWT)
{
    const int b = blockIdx.x;
    const int tid = threadIdx.x;
    __shared__ int   nsel;
    __shared__ int   s_idx[64];
    __shared__ float s_val[64];
    if (tid == 0) nsel = 0;
    __syncthreads();
    const float* lrow = latents + (size_t)b * L;
    for (int i = tid * 4; i < L; i += 1024) {
        float4 v = *reinterpret_cast<const float4*>(lrow + i);
        float vv[4] = {v.x, v.y, v.z, v.w};
        #pragma unroll
        for (int j = 0; j < 4; ++j) {
            if (vv[j] != 0.0f) {
                int p = atomicAdd(&nsel, 1);
                if (p < 64) { s_idx[p] = i + j; s_val[p] = vv[j]; }
            }
        }
    }
    __syncthreads();
    if (tid == 0) {
        int n = nsel; if (n > 64) n = 64;
        for (int a = 1; a < n; ++a) {
            int ia = s_idx[a]; float va = s_val[a];
            int c = a - 1;
            while (c >= 0 && s_idx[c] > ia) {
                s_idx[c + 1] = s_idx[c]; s_val[c + 1] = s_val[c]; --c;
            }
            s_idx[c + 1] = ia; s_val[c + 1] = va;
        }
    }
    __syncthreads();
    int n = nsel; if (n > 64) n = 64;
    float accv[3] = {0.f, 0.f, 0.f};
    if (useWT) {
        for (int j = 0; j < n; ++j) {
            const int l = s_idx[j]; const float v = s_val[j];
            const float* w = WT + (size_t)l * D;
            #pragma unroll
            for (int c = 0; c < 3; ++c) {
                int d = tid + c * 256;
                if (d < D) accv[c] = fmaf(v, w[d], accv[c]);
            }
        }
    } else {
        for (int j = 0; j < n; ++j) {
            const int l = s_idx[j]; const float v = s_val[j];
            #pragma unroll
            for (int c = 0; c < 3; ++c) {
                int d = tid + c * 256;
                if (d < D) accv[c] = fmaf(v, Wfall[(size_t)d * L + l], accv[c]);
            }
        }
    }
    #pragma unroll
    for (int c = 0; c < 3; ++c) {
        int d = tid + c * 256;
        if (d < D) recon[(size_t)b * D + d] = accv[c] + dbias[d];
    }
}

// =====================================================================
extern "C" void kernel_launch(void* const* d_in, const int* in_sizes, int n_in,
                              void* d_out, int out_size, void* d_ws, size_t ws_size,
                              hipStream_t stream)
{
    const float* x     = (const float*)d_in[0];
    const float* enc_w = (const float*)d_in[1];
    const float* enc_b = (const float*)d_in[2];
    const float* dec_w = (const float*)d_in[3];
    const float* dec_b = (const float*)d_in[4];
    const int*   kptr  = (const int*)d_in[5];

    const int D = in_sizes[4];            // 768
    const int L = in_sizes[2];            // 16384
    const int B = in_sizes[0] / D;        // 4096

    float* recon   = (float*)d_out;
    float* latents = recon + (size_t)B * D;
    float* pre     = latents + (size_t)B * L;

    // workspace layout (fast path)
    const size_t szA  = (size_t)B * D * 2;
    const size_t szW  = (size_t)L * D * 2;
    const size_t szSel = (size_t)B * 64 * 4;
    size_t off = 0;
    ushort* Ah  = (ushort*)((char*)d_ws + off); off += szA;
    ushort* Wh  = (ushort*)((char*)d_ws + off); off += szW;
    ushort* WTb = (ushort*)((char*)d_ws + off); off += szW;
    int*    sidx = (int*)((char*)d_ws + off);   off += szSel;
    float*  sval = (float*)((char*)d_ws + off); off += szSel;
    const size_t need = off;

    // 256-tile W-reuse-major mapping requires (B/256) % 8 == 0
    const bool shapes_ok = (B % 2048 == 0) && (L % 1024 == 0) && (L >= 2048) &&
                           (D % 32 == 0) && (D <= 768);
    const bool fast = shapes_ok && ws_size >= need;

    if (fast) {
        const int KT = D / 32;
        int totA = (B / 16) * KT * 64;
        pack_bf16<<<(totA + 255) / 256, 256, 0, stream>>>(x, Ah, (B / 16) * KT, KT, D);
        int totW = (L / 16) * KT * 64;
        pack_bf16<<<(totW + 255) / 256, 256, 0, stream>>>(enc_w, Wh, (L / 16) * KT, KT, D);
        transpose_bf16<<<dim3(L / 32, D / 32), dim3(32, 8), 0, stream>>>(dec_w, WTb, D, L);
        encoder_mfma256<<<(B / 256) * (L / 256), 512, 0, stream>>>(
            Ah, Wh, enc_b, pre, latents, B, L, D);
        select_refine<<<B, 256, 0, stream>>>(pre, x, enc_w, enc_b, latents, sidx, sval, kptr, D, L);
        decoder_selb<<<B, 256, 0, stream>>>(sidx, sval, WTb, dec_b, recon, kptr, D);
    } else {
        hipMemsetAsync(latents, 0, (size_t)B * L * sizeof(float), stream);
        int useWT = 0;
        const size_t szWT = (size_t)L * D * 4;
        if (ws_size >= szWT) {
            useWT = 1;
            transpose_kernel<<<dim3(L / 32, D / 32), dim3(32, 8), 0, stream>>>(dec_w, (float*)d_ws, D, L);
        }
        encoder_gemm<<<dim3(L / BN, B / BM), 256, 0, stream>>>(x, enc_w, enc_b, pre, B, L, D);
        topk_kernel<<<B, 256, 0, stream>>>(pre, latents, kptr, L);
        decoder_kernel<<<B, 256, 0, stream>>>(latents, (float*)d_ws, dec_w, dec_b, recon, L, D, useWT);
    }
}

// Round 12
// 429.734 us; speedup vs baseline: 1.1176x; 1.1176x over previous
//
#include <hip/hip_runtime.h>
#include <hip/hip_bf16.h>
#include <stdint.h>

// =====================================================================
// SparseAutoencoder forward:
//   pre     = x @ enc_w.T + enc_b          [B, L]
//   latents = topk_sparsify(pre, k)        [B, L] (k-sparse by |value|)
//   recon   = latents @ dec_w.T + dec_b    [B, D]
// d_out = concat(recon, latents, pre) flat, f32.
// B=4096, D=768, L=16384, k=32.
//
// Fast path (round-10 structure + prep fusion + decoder fusion):
//   - prep_all: one dispatch packs x->Ah, enc_w->Wh (MFMA fragment
//     order) and transposes dec_w->WTb bf16 (independent work,
//     concurrent blocks).
//   - 1-pass bf16 MFMA encoder, 128x128 tile, 2-phase dbuf,
//     W-reuse-major XCD mapping, NT stores for pre (round-10: NT keeps
//     L3 clean so staged A/W panels stay resident; +95us).
//   - select_refine: NT pre-scan + NT latents zero-fill; sampled
//     threshold collect, u64-key rank, margin-gated exact f32 recompute
//     of boundary zone (m = 1.2e-3*||x|| ~ 34 sigma); FUSED sparse
//     decoder tail (selected set already in LDS; WTb is L3-resident).
// Fallback: round-1 f32 vector path (shape mismatch only).
// =====================================================================

typedef __attribute__((ext_vector_type(8))) short bf16x8;
typedef __attribute__((ext_vector_type(4))) float f32x4;

__device__ __forceinline__ ushort f2bf_rne(float v) {
    unsigned u = __float_as_uint(v);
    return (ushort)((u + 0x7fffu + ((u >> 16) & 1u)) >> 16);
}
__device__ __forceinline__ float bf2f(ushort h) {
    return __uint_as_float(((unsigned)h) << 16);
}

// ---------------------------------------------------------------
// prep_all: fused prep (one dispatch, three independent jobs)
//   blocks [0, nA)        : pack x  -> Ah  (MFMA fragment order)
//   blocks [nA, nA+nW)    : pack enc_w -> Wh
//   blocks [nA+nW, ...)   : transpose dec_w[D][L] -> WTb[L][D] bf16
// pack layout: P[r16][kt][lane][8], lane holds row r16*16+(lane&15),
//   k = kt*32 + (lane>>4)*8 + i   (mfma_f32_16x16x32_bf16 A/B^T layout)
// ---------------------------------------------------------------
__global__ __launch_bounds__(256)
void prep_all(const float* __restrict__ x, const float* __restrict__ enc_w,
              const float* __restrict__ dec_w,
              ushort* __restrict__ Ah, ushort* __restrict__ Wh,
              ushort* __restrict__ WTb,
              int nA, int nW, int KT, int K, int D, int L)
{
    __shared__ float tile[32][33];
    const int bid = blockIdx.x;
    if (bid < nA + nW) {
        const float* X;
        ushort* P;
        int base;
        if (bid < nA) { X = x;     P = Ah; base = bid; }
        else          { X = enc_w; P = Wh; base = bid - nA; }
        int t = base * 256 + threadIdx.x;
        int lane = t & 63;
        int rest = t >> 6;
        int r16 = rest / KT, kt = rest - r16 * KT;
        int row = (r16 << 4) + (lane & 15);
        int k0  = (kt << 5) + ((lane >> 4) << 3);
        const float* src = X + (size_t)row * K + k0;
        uint hw[4];
        #pragma unroll
        for (int i = 0; i < 4; ++i) {
            float v0 = src[2 * i], v1 = src[2 * i + 1];
            hw[i] = (uint)f2bf_rne(v0) | ((uint)f2bf_rne(v1) << 16);
        }
        *reinterpret_cast<uint4*>(P + (size_t)t * 8) = make_uint4(hw[0], hw[1], hw[2], hw[3]);
    } else {
        int tb = bid - nA - nW;
        int gx = L >> 5;
        int l0 = (tb % gx) << 5;
        int d0 = (tb / gx) << 5;
        int tx = threadIdx.x & 31;
        int ty = threadIdx.x >> 5;
        for (int i = ty; i < 32; i += 8)
            tile[i][tx] = dec_w[(size_t)(d0 + i) * L + (l0 + tx)];
        __syncthreads();
        for (int i = ty; i < 32; i += 8)
            WTb[(size_t)(l0 + i) * D + (d0 + tx)] = f2bf_rne(tile[tx][i]);
    }
}

// ---------------------------------------------------------------
// encoder MFMA GEMM (1-pass, BK=32, 2-phase dbuf): C = Ah*Wh^T + bias
// 128x128 tile, 4 waves (each 64x64 = 4x4 frags of 16x16x32).
// W-reuse-major mapping + NT stores for C (no L3 allocation).
// ---------------------------------------------------------------
__global__ __launch_bounds__(256, 4)
void encoder_mfma1(const ushort* __restrict__ Ah, const ushort* __restrict__ Wh,
                   const float* __restrict__ bias, float* __restrict__ C,
                   int M, int N, int K)
{
    __shared__ ushort lds[2][8192];   // 2 x 16KB: A [0,4096) | W [4096,8192)
    const int KT = K >> 5;
    const int tid  = threadIdx.x;
    const int lane = tid & 63;
    const int wid  = tid >> 6;

    // W-reuse-major XCD mapping (requires (M/128) % 8 == 0, launch-checked)
    const int gy    = M >> 7;          // row panels
    const int rpx   = gy >> 3;         // row panels per XCD
    const int xcd   = blockIdx.x & 7;
    const int local = blockIdx.x >> 3;
    const int by    = xcd * rpx + (local % rpx);
    const int bx    = local / rpx;

    const int wr = wid >> 1, wc = wid & 1;

    f32x4 acc[4][4];
    #pragma unroll
    for (int m = 0; m < 4; ++m)
        #pragma unroll
        for (int n = 0; n < 4; ++n) acc[m][n] = (f32x4){0.f, 0.f, 0.f, 0.f};

    // stage 16 chunks of 1KB into lds[buf]; wave w stages chunks [w*4,w*4+4)
    auto STAGE = [&](int buf, int kt) {
        #pragma unroll
        for (int c0 = 0; c0 < 4; ++c0) {
            int c   = (wid << 2) + c0;                 // 0..15
            int fr  = c & 7;                            // r16 group in tile
            int rb  = ((c < 8) ? (by << 3) : (bx << 3)) + fr;
            const ushort* g = ((c < 8) ? Ah : Wh) + (((size_t)rb * KT + kt) * 64 + lane) * 8;
            ushort* dst = &lds[buf][c * 512];
            __builtin_amdgcn_global_load_lds(
                (const __attribute__((address_space(1))) unsigned int*)g,
                (__attribute__((address_space(3))) unsigned int*)dst, 16, 0, 0);
        }
    };

    STAGE(0, 0);
    __syncthreads();                // prologue: buf0 ready

    int cur = 0;
    for (int kt = 0; kt < KT; ++kt) {
        if (kt + 1 < KT) STAGE(cur ^ 1, kt + 1);   // issue next-tile loads FIRST

        bf16x8 ah[4], bh[4];
        #pragma unroll
        for (int m = 0; m < 4; ++m)
            ah[m] = *reinterpret_cast<const bf16x8*>(&lds[cur][((wr << 2) + m) * 512 + lane * 8]);
        #pragma unroll
        for (int n = 0; n < 4; ++n)
            bh[n] = *reinterpret_cast<const bf16x8*>(&lds[cur][4096 + ((wc << 2) + n) * 512 + lane * 8]);

        #pragma unroll
        for (int m = 0; m < 4; ++m)
            #pragma unroll
            for (int n = 0; n < 4; ++n)
                acc[m][n] = __builtin_amdgcn_mfma_f32_16x16x32_bf16(ah[m], bh[n], acc[m][n], 0, 0, 0);

        __syncthreads();            // drains next-tile loads (overlapped w/ MFMA)
        cur ^= 1;
    }

    // epilogue: C/D layout col=lane&15, row=(lane>>4)*4+reg
    // NT stores: keep the 268MB pre stream out of L3 so W/A stay resident.
    const int r_in = (lane >> 4) << 2;
    const int c_in = lane & 15;
    #pragma unroll
    for (int n = 0; n < 4; ++n) {
        const int gc = (bx << 7) + (wc << 6) + (n << 4) + c_in;
        const float bv = bias[gc];
        #pragma unroll
        for (int m = 0; m < 4; ++m) {
            const int gr0 = (by << 7) + (wr << 6) + (m << 4) + r_in;
            #pragma unroll
            for (int q = 0; q < 4; ++q)
                __builtin_nontemporal_store(acc[m][n][q] + bv,
                                            &C[(size_t)(gr0 + q) * N + gc]);
        }
    }
}

// ---------------------------------------------------------------
// select_refine (+fused decoder): per row,
//  1) stage x; 2) sampled threshold (256 samples; tiers), collect |v|>=t
//     (NT loads: pre has no reuse; keep enc_w/WTb in L3)
//  3) zero latents row (NT stores); 4) u64-key rank -> approx k-th (tk)
//  5) zone = |a - tk| <= m -> exact f32 recompute (cooperative dots)
//  6) final = {a > tk+m} + top(k - A) of zone by exact value
//  7) deterministic slot ranking; scatter latents, emit (idx,val) list
//  8) FUSED decoder: recon[b] = sum_j fin_v[j] * WTb[fin_i[j]] + dec_b
// ---------------------------------------------------------------
#define SR_CAP 1024
#define SR_ZCAP 128

__global__ __launch_bounds__(256, 8)
void select_refine(const float* __restrict__ pre, const float* __restrict__ x,
                   const float* __restrict__ enc_w, const float* __restrict__ enc_b,
                   float* __restrict__ latents, int* __restrict__ sel_idx,
                   float* __restrict__ sel_val, const int* __restrict__ kptr,
                   const ushort* __restrict__ WT, const float* __restrict__ dbias,
                   float* __restrict__ recon, int D, int L)
{
    const int b   = blockIdx.x;
    const int tid = threadIdx.x;
    const float* row = pre + (size_t)b * L;
    float* lrow = latents + (size_t)b * L;

    __shared__ float    xs[768];
    __shared__ float    smp[256];
    __shared__ float    sthr[3];     // [0]=rank1 (~L/128), [1]=rank3 (~L/64), [2]=rank7 (~L/32)
    __shared__ int      cnt;
    __shared__ unsigned long long lkey[SR_CAP];
    __shared__ float    lval[SR_CAP];
    __shared__ float    s_tk;
    __shared__ float    s_xn2;
    __shared__ int      zidx[SR_ZCAP];
    __shared__ float    zval[SR_ZCAP];
    __shared__ int      zn;
    __shared__ int      fin_n;
    __shared__ int      fin_i[64];
    __shared__ float    fin_v[64];
    __shared__ float    red[4];

    int k = *kptr; if (k > 64) k = 64; if (k < 1) k = 1;

    // ---- stage x row; compute ||x||^2 for margin scaling ----
    float xn2p = 0.f;
    for (int i = tid; i < D; i += 256) {
        float v = x[(size_t)b * D + i];
        xs[i] = v;
        xn2p = fmaf(v, v, xn2p);
    }
    #pragma unroll
    for (int off = 32; off > 0; off >>= 1) xn2p += __shfl_down(xn2p, off);
    if ((tid & 63) == 0) red[tid >> 6] = xn2p;
    if (tid == 0) { zn = 0; fin_n = 0; }
    __syncthreads();
    if (tid == 0) s_xn2 = red[0] + red[1] + red[2] + red[3];

    // ---- samples + threshold tiers ----
    const int stride = L >> 8;
    smp[tid] = fabsf(row[(size_t)tid * stride]);
    __syncthreads();
    {
        float s = smp[tid];
        int r = 0;
        for (int j = 0; j < 256; ++j) {
            float o = smp[j];
            r += (o > s || (o == s && j < tid)) ? 1 : 0;
        }
        if (r == 1) sthr[0] = s;   // overflow retry
        if (r == 3) sthr[1] = s;   // primary (~256 survivors)
        if (r == 7) sthr[2] = s;   // underflow retry (~512)
    }
    __syncthreads();

    // ---- collect with retry tiers (NT loads of pre) ----
    float t = sthr[1];
    int n = 0;
    for (int attempt = 0; attempt < 2; ++attempt) {
        __syncthreads();
        if (tid == 0) cnt = 0;
        __syncthreads();
        for (int i = tid * 4; i < L; i += 1024) {
            f32x4 v = __builtin_nontemporal_load(
                reinterpret_cast<const f32x4*>(row + i));
            float vv[4] = {v.x, v.y, v.z, v.w};
            #pragma unroll
            for (int j = 0; j < 4; ++j) {
                float av = fabsf(vv[j]);
                if (av >= t) {
                    int p = atomicAdd(&cnt, 1);
                    if (p < SR_CAP) {
                        lkey[p] = ((unsigned long long)__float_as_uint(av) << 32)
                                  | (unsigned)(~(i + j));
                        lval[p] = vv[j];
                    }
                }
            }
        }
        __syncthreads();
        n = cnt;
        if (n >= 48 && n <= SR_CAP) break;
        t = (n < 48) ? sthr[2] : sthr[0];
    }
    if (n > SR_CAP) n = SR_CAP;
    if (k > n) k = n;

    // ---- zero-fill latents row (NT stores; replaces global memset) ----
    const f32x4 z4 = (f32x4){0.f, 0.f, 0.f, 0.f};
    for (int i = tid * 4; i < L; i += 1024)
        __builtin_nontemporal_store(z4, reinterpret_cast<f32x4*>(lrow + i));

    // ---- rank pass: find approx k-th largest (tk) ----
    for (int i = tid; i < n; i += 256) {
        unsigned long long ki = lkey[i];
        int rk = 0;
        for (int j = 0; j < n; ++j) rk += (lkey[j] > ki) ? 1 : 0;
        if (rk == k - 1) s_tk = fabsf(lval[i]);
    }
    __syncthreads();

    const float tk = s_tk;
    // margin: err sigma ~3.5e-5*||x||; need >= 2*e_max (~12 sigma). 34 sigma.
    const float m  = 1.2e-3f * sqrtf(s_xn2);

    // ---- partition: clear-selected (a > tk+m) vs zone (|a-tk| <= m) ----
    for (int i = tid; i < n; i += 256) {
        float a = fabsf(lval[i]);
        if (a > tk + m) {
            int p = atomicAdd(&fin_n, 1);     // guaranteed < k
            fin_i[p] = (int)(~(unsigned)lkey[i]);
            fin_v[p] = lval[i];
        } else if (a >= tk - m) {
            int zp = atomicAdd(&zn, 1);
            if (zp < SR_ZCAP) zidx[zp] = (int)(~(unsigned)lkey[i]);
        }
    }
    __syncthreads();
    const int A  = fin_n;
    const int nz = (zn < SR_ZCAP) ? zn : SR_ZCAP;

    // ---- exact f32 dots for zone members ----
    for (int z = 0; z < nz; ++z) {
        const int l = zidx[z];
        const float* wrow = enc_w + (size_t)l * D;
        float s = 0.f;
        for (int d = tid; d < D; d += 256) s = fmaf(xs[d], wrow[d], s);
        #pragma unroll
        for (int off = 32; off > 0; off >>= 1) s += __shfl_down(s, off);
        if ((tid & 63) == 0) red[tid >> 6] = s;
        __syncthreads();
        if (tid == 0) zval[z] = red[0] + red[1] + red[2] + red[3] + enc_b[l];
        __syncthreads();
    }

    // ---- select top (k - A) of zone by exact (|value| desc, idx asc) ----
    const int k2 = k - A;
    if (tid < nz) {
        float az = fabsf(zval[tid]);
        int   iz = zidx[tid];
        int rz = 0;
        for (int j = 0; j < nz; ++j) {
            float aj = fabsf(zval[j]);
            rz += (aj > az || (aj == az && zidx[j] < iz)) ? 1 : 0;
        }
        if (rz < k2) {
            int p = atomicAdd(&fin_n, 1);
            if (p < 64) { fin_i[p] = iz; fin_v[p] = zval[tid]; }
        }
    }
    __syncthreads();

    // ---- deterministic final slots + writes ----
    int fn = fin_n; if (fn > 64) fn = 64;
    if (tid < fn) {
        float av = fabsf(fin_v[tid]);
        int   ii = fin_i[tid];
        int fr = 0;
        for (int j = 0; j < fn; ++j) {
            float aj = fabsf(fin_v[j]);
            fr += (aj > av || (aj == av && fin_i[j] < ii)) ? 1 : 0;
        }
        sel_idx[(size_t)b * 64 + fr] = ii;
        sel_val[(size_t)b * 64 + fr] = fin_v[tid];
        lrow[ii] = fin_v[tid];
    }
    if (tid >= fn && tid < k) {          // pathological safety fill
        sel_idx[(size_t)b * 64 + tid] = 0;
        sel_val[(size_t)b * 64 + tid] = 0.f;
    }
    __syncthreads();

    // ---- FUSED decoder: recon[b] = sum_j fin_v[j]*WT[fin_i[j]] + dbias ----
    float a0 = 0.f, a1 = 0.f, a2 = 0.f;
    for (int j = 0; j < fn; ++j) {
        const ushort* w = WT + (size_t)fin_i[j] * D;
        const float v = fin_v[j];
        if (tid < D)        a0 = fmaf(v, bf2f(w[tid]),       a0);
        if (tid + 256 < D)  a1 = fmaf(v, bf2f(w[tid + 256]), a1);
        if (tid + 512 < D)  a2 = fmaf(v, bf2f(w[tid + 512]), a2);
    }
    if (tid < D)
        __builtin_nontemporal_store(a0 + dbias[tid],       &recon[(size_t)b * D + tid]);
    if (tid + 256 < D)
        __builtin_nontemporal_store(a1 + dbias[tid + 256], &recon[(size_t)b * D + tid + 256]);
    if (tid + 512 < D)
        __builtin_nontemporal_store(a2 + dbias[tid + 512], &recon[(size_t)b * D + tid + 512]);
}

// =====================================================================
// ============== round-1 fallback kernels (f32 path) ==================
// =====================================================================
#define BM 128
#define BN 128
#define BKT 16

__global__ __launch_bounds__(256, 2)
void encoder_gemm(const float* __restrict__ A, const float* __restrict__ Bw,
                  const float* __restrict__ bias, float* __restrict__ C,
                  int M, int N, int K)
{
    __shared__ float As[BKT][BM + 4];
    __shared__ float Bs[BKT][BN + 4];
    const int tid  = threadIdx.x;
    const int row0 = blockIdx.y * BM;
    const int col0 = blockIdx.x * BN;
    const int lrow = tid >> 2;
    const int lc4  = (tid & 3) * 4;
    const int ty = tid >> 4;
    const int tx = tid & 15;
    float acc[2][2][4][4];
    #pragma unroll
    for (int a = 0; a < 2; ++a)
        #pragma unroll
        for (int b = 0; b < 2; ++b)
            #pragma unroll
            for (int i = 0; i < 4; ++i)
                #pragma unroll
                for (int j = 0; j < 4; ++j) acc[a][b][i][j] = 0.f;
    for (int k0 = 0; k0 < K; k0 += BKT) {
        float4 a0 = *reinterpret_cast<const float4*>(A + (size_t)(row0 + lrow)      * K + k0 + lc4);
        float4 a1 = *reinterpret_cast<const float4*>(A + (size_t)(row0 + lrow + 64) * K + k0 + lc4);
        float4 b0 = *reinterpret_cast<const float4*>(Bw + (size_t)(col0 + lrow)      * K + k0 + lc4);
        float4 b1 = *reinterpret_cast<const float4*>(Bw + (size_t)(col0 + lrow + 64) * K + k0 + lc4);
        __syncthreads();
        As[lc4 + 0][lrow] = a0.x; As[lc4 + 1][lrow] = a0.y;
        As[lc4 + 2][lrow] = a0.z; As[lc4 + 3][lrow] = a0.w;
        As[lc4 + 0][lrow + 64] = a1.x; As[lc4 + 1][lrow + 64] = a1.y;
        As[lc4 + 2][lrow + 64] = a1.z; As[lc4 + 3][lrow + 64] = a1.w;
        Bs[lc4 + 0][lrow] = b0.x; Bs[lc4 + 1][lrow] = b0.y;
        Bs[lc4 + 2][lrow] = b0.z; Bs[lc4 + 3][lrow] = b0.w;
        Bs[lc4 + 0][lrow + 64] = b1.x; Bs[lc4 + 1][lrow + 64] = b1.y;
        Bs[lc4 + 2][lrow + 64] = b1.z; Bs[lc4 + 3][lrow + 64] = b1.w;
        __syncthreads();
        #pragma unroll
        for (int kk = 0; kk < BKT; ++kk) {
            float av[2][4], bv[2][4];
            *reinterpret_cast<float4*>(av[0]) = *reinterpret_cast<const float4*>(&As[kk][ty * 4]);
            *reinterpret_cast<float4*>(av[1]) = *reinterpret_cast<const float4*>(&As[kk][ty * 4 + 64]);
            *reinterpret_cast<float4*>(bv[0]) = *reinterpret_cast<const float4*>(&Bs[kk][tx * 4]);
            *reinterpret_cast<float4*>(bv[1]) = *reinterpret_cast<const float4*>(&Bs[kk][tx * 4 + 64]);
            #pragma unroll
            for (int a = 0; a < 2; ++a)
                #pragma unroll
                for (int i = 0; i < 4; ++i)
                    #pragma unroll
                    for (int b = 0; b < 2; ++b)
                        #pragma unroll
                        for (int j = 0; j < 4; ++j)
                            acc[a][b][i][j] = fmaf(av[a][i], bv[b][j], acc[a][b][i][j]);
        }
    }
    #pragma unroll
    for (int a = 0; a < 2; ++a)
        #pragma unroll
        for (int i = 0; i < 4; ++i) {
            const int r = row0 + a * 64 + ty * 4 + i;
            #pragma unroll
            for (int b = 0; b < 2; ++b) {
                const int c = col0 + b * 64 + tx * 4;
                float4 o;
                o.x = acc[a][b][i][0] + bias[c + 0];
                o.y = acc[a][b][i][1] + bias[c + 1];
                o.z = acc[a][b][i][2] + bias[c + 2];
                o.w = acc[a][b][i][3] + bias[c + 3];
                *reinterpret_cast<float4*>(C + (size_t)r * N + c) = o;
            }
        }
}

__global__ __launch_bounds__(256)
void topk_kernel(const float* __restrict__ pre, float* __restrict__ latents,
                 const int* __restrict__ kptr, int L)
{
    const int b   = blockIdx.x;
    const int tid = threadIdx.x;
    int k = *kptr; if (k > 64) k = 64; if (k < 1) k = 1;
    const float* row = pre + (size_t)b * L;
    __shared__ unsigned hist[2048];
    __shared__ unsigned coarse[256];
    __shared__ unsigned sh_cgt, sh_prefix;
    __shared__ int      tie_n;
    __shared__ int      tie_idx[1024];
    __shared__ float    tie_val[1024];
    unsigned cgt = 0, prefix = 0;
    for (int level = 0; level < 3; ++level) {
        const int nb     = (level == 0) ? 2048 : 1024;
        const int shift  = (level == 0) ? 20 : (level == 1 ? 10 : 0);
        const int pshift = (level == 1) ? 20 : 10;
        for (int i = tid; i < nb; i += 256) hist[i] = 0;
        __syncthreads();
        for (int i = tid * 4; i < L; i += 1024) {
            float4 v = *reinterpret_cast<const float4*>(row + i);
            float vv[4] = {v.x, v.y, v.z, v.w};
            #pragma unroll
            for (int j = 0; j < 4; ++j) {
                unsigned key = __float_as_uint(vv[j]) & 0x7fffffffu;
                if (level == 0 || (key >> pshift) == prefix)
                    atomicAdd(&hist[(key >> shift) & (nb - 1)], 1u);
            }
        }
        __syncthreads();
        const int per = nb / 256;
        unsigned s = 0;
        for (int j = 0; j < per; ++j) s += hist[tid * per + j];
        coarse[tid] = s;
        __syncthreads();
        if (tid == 0) {
            unsigned run = cgt;
            int bin = 0;
            for (int c = 255; c >= 0; --c) {
                if (run + coarse[c] >= (unsigned)k) {
                    bin = c * per + per - 1;
                    for (; bin > c * per; --bin) {
                        if (run + hist[bin] >= (unsigned)k) break;
                        run += hist[bin];
                    }
                    break;
                }
                run += coarse[c];
            }
            sh_cgt = run;
            sh_prefix = (level == 0) ? (unsigned)bin : ((prefix << 10) | (unsigned)bin);
        }
        __syncthreads();
        cgt = sh_cgt; prefix = sh_prefix;
        __syncthreads();
    }
    const unsigned T = prefix;
    const int r = k - (int)cgt;
    if (tid == 0) tie_n = 0;
    __syncthreads();
    float* lrow = latents + (size_t)b * L;
    for (int i = tid * 4; i < L; i += 1024) {
        float4 v = *reinterpret_cast<const float4*>(row + i);
        float vv[4] = {v.x, v.y, v.z, v.w};
        #pragma unroll
        for (int j = 0; j < 4; ++j) {
            unsigned key = __float_as_uint(vv[j]) & 0x7fffffffu;
            if (key > T) {
                lrow[i + j] = vv[j];
            } else if (key == T) {
                int p = atomicAdd(&tie_n, 1);
                if (p < 1024) { tie_idx[p] = i + j; tie_val[p] = vv[j]; }
            }
        }
    }
    __syncthreads();
    if (tid == 0) {
        int nn = tie_n; if (nn > 1024) nn = 1024;
        for (int a = 1; a < nn; ++a) {
            int ia = tie_idx[a]; float va = tie_val[a];
            int c = a - 1;
            while (c >= 0 && tie_idx[c] > ia) {
                tie_idx[c + 1] = tie_idx[c]; tie_val[c + 1] = tie_val[c]; --c;
            }
            tie_idx[c + 1] = ia; tie_val[c + 1] = va;
        }
        int take = r < nn ? r : nn;
        for (int a = 0; a < take; ++a) lrow[tie_idx[a]] = tie_val[a];
    }
}

__global__ void transpose_kernel(const float* __restrict__ W, float* __restrict__ WT,
                                 int D, int L)
{
    __shared__ float tile[32][33];
    const int l0 = blockIdx.x * 32;
    const int d0 = blockIdx.y * 32;
    const int tx = threadIdx.x;
    const int ty = threadIdx.y;
    for (int i = ty; i < 32; i += 8)
        tile[i][tx] = W[(size_t)(d0 + i) * L + (l0 + tx)];
    __syncthreads();
    for (int i = ty; i < 32; i += 8)
        WT[(size_t)(l0 + i) * D + (d0 + tx)] = tile[tx][i];
}

__global__ __launch_bounds__(256)
void decoder_kernel(const float* __restrict__ latents, const float* __restrict__ WT,
                    const float* __restrict__ Wfall, const float* __restrict__ dbias,
                    float* __restrict__ recon, int L, int D, int useWT)
{
    const int b = blockIdx.x;
    const int tid = threadIdx.x;
    __shared__ int   nsel;
    __shared__ int   s_idx[64];
    __shared__ float s_val[64];
    if (tid == 0) nsel = 0;
    __syncthreads();
    const float* lrow = latents + (size_t)b * L;
    for (int i = tid * 4; i < L; i += 1024) {
        float4 v = *reinterpret_cast<const float4*>(lrow + i);
        float vv[4] = {v.x, v.y, v.z, v.w};
        #pragma unroll
        for (int j = 0; j < 4; ++j) {
            if (vv[j] != 0.0f) {
                int p = atomicAdd(&nsel, 1);
                if (p < 64) { s_idx[p] = i + j; s_val[p] = vv[j]; }
            }
        }
    }
    __syncthreads();
    if (tid == 0) {
        int n = nsel; if (n > 64) n = 64;
        for (int a = 1; a < n; ++a) {
            int ia = s_idx[a]; float va = s_val[a];
            int c = a - 1;
            while (c >= 0 && s_idx[c] > ia) {
                s_idx[c + 1] = s_idx[c]; s_val[c + 1] = s_val[c]; --c;
            }
            s_idx[c + 1] = ia; s_val[c + 1] = va;
        }
    }
    __syncthreads();
    int n = nsel; if (n > 64) n = 64;
    float accv[3] = {0.f, 0.f, 0.f};
    if (useWT) {
        for (int j = 0; j < n; ++j) {
            const int l = s_idx[j]; const float v = s_val[j];
            const float* w = WT + (size_t)l * D;
            #pragma unroll
            for (int c = 0; c < 3; ++c) {
                int d = tid + c * 256;
                if (d < D) accv[c] = fmaf(v, w[d], accv[c]);
            }
        }
    } else {
        for (int j = 0; j < n; ++j) {
            const int l = s_idx[j]; const float v = s_val[j];
            #pragma unroll
            for (int c = 0; c < 3; ++c) {
                int d = tid + c * 256;
                if (d < D) accv[c] = fmaf(v, Wfall[(size_t)d * L + l], accv[c]);
            }
        }
    }
    #pragma unroll
    for (int c = 0; c < 3; ++c) {
        int d = tid + c * 256;
        if (d < D) recon[(size_t)b * D + d] = accv[c] + dbias[d];
    }
}

// =====================================================================
extern "C" void kernel_launch(void* const* d_in, const int* in_sizes, int n_in,
                              void* d_out, int out_size, void* d_ws, size_t ws_size,
                              hipStream_t stream)
{
    const float* x     = (const float*)d_in[0];
    const float* enc_w = (const float*)d_in[1];
    const float* enc_b = (const float*)d_in[2];
    const float* dec_w = (const float*)d_in[3];
    const float* dec_b = (const float*)d_in[4];
    const int*   kptr  = (const int*)d_in[5];

    const int D = in_sizes[4];            // 768
    const int L = in_sizes[2];            // 16384
    const int B = in_sizes[0] / D;        // 4096

    float* recon   = (float*)d_out;
    float* latents = recon + (size_t)B * D;
    float* pre     = latents + (size_t)B * L;

    // workspace layout (fast path)
    const size_t szA  = (size_t)B * D * 2;
    const size_t szW  = (size_t)L * D * 2;
    const size_t szSel = (size_t)B * 64 * 4;
    size_t off = 0;
    ushort* Ah  = (ushort*)((char*)d_ws + off); off += szA;
    ushort* Wh  = (ushort*)((char*)d_ws + off); off += szW;
    ushort* WTb = (ushort*)((char*)d_ws + off); off += szW;
    int*    sidx = (int*)((char*)d_ws + off);   off += szSel;
    float*  sval = (float*)((char*)d_ws + off); off += szSel;
    const size_t need = off;

    // W-reuse-major mapping requires (B/128) % 8 == 0; prep grid needs
    // pack totals divisible by 256 (guaranteed by B,L % 1024, D % 32).
    const bool shapes_ok = (B % 1024 == 0) && (L % 1024 == 0) && (L >= 2048) &&
                           (D % 32 == 0) && (D <= 768);
    const bool fast = shapes_ok && ws_size >= need;

    if (fast) {
        const int KT = D / 32;
        const int nA = (B / 16) * KT * 64 / 256;
        const int nW = (L / 16) * KT * 64 / 256;
        const int nT = (L / 32) * (D / 32);
        prep_all<<<nA + nW + nT, 256, 0, stream>>>(x, enc_w, dec_w, Ah, Wh, WTb,
                                                   nA, nW, KT, D, D, L);
        encoder_mfma1<<<(B / 128) * (L / 128), 256, 0, stream>>>(Ah, Wh, enc_b, pre, B, L, D);
        select_refine<<<B, 256, 0, stream>>>(pre, x, enc_w, enc_b, latents, sidx, sval,
                                             kptr, WTb, dec_b, recon, D, L);
    } else {
        hipMemsetAsync(latents, 0, (size_t)B * L * sizeof(float), stream);
        int useWT = 0;
        const size_t szWT = (size_t)L * D * 4;
        if (ws_size >= szWT) {
            useWT = 1;
            transpose_kernel<<<dim3(L / 32, D / 32), dim3(32, 8), 0, stream>>>(dec_w, (float*)d_ws, D, L);
        }
        encoder_gemm<<<dim3(L / BN, B / BM), 256, 0, stream>>>(x, enc_w, enc_b, pre, B, L, D);
        topk_kernel<<<B, 256, 0, stream>>>(pre, latents, kptr, L);
        decoder_kernel<<<B, 256, 0, stream>>>(latents, (float*)d_ws, dec_w, dec_b, recon, L, D, useWT);
    }
}